// Round 1
// baseline (128.837 us; speedup 1.0000x reference)
//
#include <hip/hip_runtime.h>
#include <math.h>

// Problem constants (from reference)
#define NW   16384      // B*S words
#define Tt   16         // chars per word
#define Vv   262        // vocab
#define Ee   64         // embed dim
#define Hh   32         // GRU hidden per direction
#define G3   96         // 3*H

// ws layout (floats):
//   [0, GELEMS)              : G table  [2][Vv][96]  = emb@Wih^T + bih (+bhh for r,z)
//   [GELEMS, GELEMS+WTELEMS) : WhhT     [2][32][96]  (transposed Whh for coalesced loads)
#define GELEMS  (2*Vv*G3)   // 50304
#define WTOFF   GELEMS
#define WTELEMS (2*Hh*G3)   // 6144

__device__ __forceinline__ float sigm(float x) {
    return __builtin_amdgcn_rcpf(1.0f + __expf(-x));
}
__device__ __forceinline__ float tanh_fast(float x) {
    // tanh(x) = 1 - 2/(1+e^{2x}); saturates correctly for |x| large
    return 1.0f - 2.0f * __builtin_amdgcn_rcpf(1.0f + __expf(2.0f * x));
}

// ---------------------------------------------------------------------------
// Precompute: G[dir][v][g] = sum_e emb[v,e]*Wih[g,e] + bih[g] + (g<64 ? bhh[g] : 0)
// and WhhT[dir][k][g] = Whh[dir][g][k]
// ---------------------------------------------------------------------------
__global__ __launch_bounds__(256) void precomp(
    const float* __restrict__ emb,
    const float* __restrict__ Wih_f, const float* __restrict__ Whh_f,
    const float* __restrict__ bih_f, const float* __restrict__ bhh_f,
    const float* __restrict__ Wih_b, const float* __restrict__ Whh_b,
    const float* __restrict__ bih_b, const float* __restrict__ bhh_b,
    float* __restrict__ ws)
{
    int idx = blockIdx.x * 256 + threadIdx.x;
    if (idx < GELEMS) {
        int dir = idx / (Vv * G3);
        int rem = idx - dir * (Vv * G3);
        int v = rem / G3;
        int g = rem - v * G3;
        const float* Wih = dir ? Wih_b : Wih_f;
        float acc = (dir ? bih_b : bih_f)[g];
        if (g < 2 * Hh) acc += (dir ? bhh_b : bhh_f)[g];   // fold bhh for r,z only
        const float4* er = (const float4*)(emb + v * Ee);
        const float4* wr = (const float4*)(Wih + g * Ee);
        float s = 0.0f;
        #pragma unroll
        for (int e = 0; e < Ee / 4; ++e) {
            float4 a = er[e], b = wr[e];
            s = fmaf(a.x, b.x, s);
            s = fmaf(a.y, b.y, s);
            s = fmaf(a.z, b.z, s);
            s = fmaf(a.w, b.w, s);
        }
        ws[idx] = acc + s;
    } else if (idx < GELEMS + WTELEMS) {
        int r2  = idx - GELEMS;
        int dir = r2 / (Hh * G3);
        int r3  = r2 - dir * (Hh * G3);
        int k   = r3 / G3;
        int g   = r3 - k * G3;
        ws[idx] = (dir ? Whh_b : Whh_f)[g * Hh + k];
    }
}

// ---------------------------------------------------------------------------
// Main: one 32-lane half-wave per (word, direction). Lane j owns h[j].
// Block = 256 threads = 4 words x 2 dirs x 32 lanes. No __syncthreads needed:
// each task lives entirely inside one wave (lanes 0-31 dir0, 32-63 dir1).
// ---------------------------------------------------------------------------
__global__ __launch_bounds__(256) void gru_main(
    const int*   __restrict__ x,
    const float* __restrict__ ws,
    const float* __restrict__ bhh_f,
    const float* __restrict__ bhh_b,
    float*       __restrict__ out)
{
    __shared__ float lds_h[256];           // [4 words][2 dirs][32]
    const int tid  = threadIdx.x;
    const int j    = tid & 31;
    const int dir  = (tid >> 5) & 1;
    const int w    = tid >> 6;
    const int word = blockIdx.x * 4 + w;

    const float* Gt = ws + dir * (Vv * G3);
    const float* Wt = ws + WTOFF + dir * (Hh * G3);

    // Whh rows j (r), j+32 (z), j+64 (n) into registers, coalesced via WhhT
    float wr[Hh], wz[Hh], wn[Hh];
    #pragma unroll
    for (int k = 0; k < Hh; ++k) {
        const float* p = Wt + k * G3;
        wr[k] = p[j];
        wz[k] = p[32 + j];
        wn[k] = p[64 + j];
    }
    const float bn = (dir ? bhh_b : bhh_f)[64 + j];   // bhh_n stays inside r*( )

    const int* xw = x + word * Tt;
    const int  t0 = dir ? (Tt - 1) : 0;
    const int  sg = dir ? -1 : 1;

    float* hs = lds_h + (tid >> 5) * Hh;   // this task's h[0..31]
    hs[j] = 0.0f;
    float h = 0.0f;
    float hmax = -1e30f;

    // software-pipeline the gi table lookups one step ahead
    int c0 = xw[t0];
    float grn = Gt[c0 * G3 + j];
    float gzn = Gt[c0 * G3 + 32 + j];
    float gnn = Gt[c0 * G3 + 64 + j];

    #pragma unroll
    for (int t = 0; t < Tt; ++t) {
        const float gr = grn, gz = gzn, gn = gnn;
        if (t < Tt - 1) {
            int c2 = xw[t0 + (t + 1) * sg];
            grn = Gt[c2 * G3 + j];
            gzn = Gt[c2 * G3 + 32 + j];
            gnn = Gt[c2 * G3 + 64 + j];
        }

        // gh = Whh @ h : 3 dots of length 32; h read broadcast from LDS
        float accr = 0.0f, accz = 0.0f, accn = 0.0f;
        const float4* h4 = (const float4*)hs;
        #pragma unroll
        for (int q = 0; q < 8; ++q) {
            float4 hv = h4[q];
            accr = fmaf(wr[4*q+0], hv.x, accr);
            accr = fmaf(wr[4*q+1], hv.y, accr);
            accr = fmaf(wr[4*q+2], hv.z, accr);
            accr = fmaf(wr[4*q+3], hv.w, accr);
            accz = fmaf(wz[4*q+0], hv.x, accz);
            accz = fmaf(wz[4*q+1], hv.y, accz);
            accz = fmaf(wz[4*q+2], hv.z, accz);
            accz = fmaf(wz[4*q+3], hv.w, accz);
            accn = fmaf(wn[4*q+0], hv.x, accn);
            accn = fmaf(wn[4*q+1], hv.y, accn);
            accn = fmaf(wn[4*q+2], hv.z, accn);
            accn = fmaf(wn[4*q+3], hv.w, accn);
        }

        float r = sigm(gr + accr);
        float z = sigm(gz + accz);
        float n = tanh_fast(fmaf(r, accn + bn, gn));
        h = n + z * (h - n);                 // (1-z)*n + z*h
        hmax = fmaxf(hmax, h);
        hs[j] = h;                           // in-wave ordering, no barrier
    }

    out[word * 64 + dir * 32 + j] = hmax;
}

extern "C" void kernel_launch(void* const* d_in, const int* in_sizes, int n_in,
                              void* d_out, int out_size, void* d_ws, size_t ws_size,
                              hipStream_t stream) {
    const int*   x     = (const int*)  d_in[0];
    const float* emb   = (const float*)d_in[1];
    const float* Wih_f = (const float*)d_in[2];
    const float* Whh_f = (const float*)d_in[3];
    const float* bih_f = (const float*)d_in[4];
    const float* bhh_f = (const float*)d_in[5];
    const float* Wih_b = (const float*)d_in[6];
    const float* Whh_b = (const float*)d_in[7];
    const float* bih_b = (const float*)d_in[8];
    const float* bhh_b = (const float*)d_in[9];
    float* out = (float*)d_out;
    float* ws  = (float*)d_ws;

    int pre_threads = GELEMS + WTELEMS;                 // 56448
    int pre_blocks  = (pre_threads + 255) / 256;        // 221
    precomp<<<pre_blocks, 256, 0, stream>>>(emb, Wih_f, Whh_f, bih_f, bhh_f,
                                            Wih_b, Whh_b, bih_b, bhh_b, ws);

    gru_main<<<NW / 4, 256, 0, stream>>>(x, ws, bhh_f, bhh_b, out);
}

// Round 2
// 96.438 us; speedup vs baseline: 1.3360x; 1.3360x over previous
//
#include <hip/hip_runtime.h>
#include <math.h>

// Problem constants
#define NW 16384      // B*S words
#define Tt 16         // chars per word
#define Vv 262        // vocab
#define Ee 64         // embed dim
#define Hh 32         // GRU hidden per direction
#define G3 96         // 3*H

// ws layout (floats):
//   [0, GFLOATS)      G table [2][262][96] = emb@Wih^T + bih (+bhh for r,z gates)
//   [BHI_FOFF, +3072) Whh B-fragments, bf16 hi parts  [2][6][64 lanes][8] ushort
//   [BLO_FOFF, +3072) Whh B-fragments, bf16 lo parts
#define GFLOATS  (2*Vv*G3)          // 50304
#define BHI_FOFF GFLOATS
#define BLO_FOFF (GFLOATS + 3072)

typedef float        f32x4  __attribute__((ext_vector_type(4)));
typedef short        bf16x8 __attribute__((ext_vector_type(8)));
typedef unsigned int u32;
typedef u32          u32x4  __attribute__((ext_vector_type(4)));
typedef int          i32x4  __attribute__((ext_vector_type(4)));

__device__ __forceinline__ unsigned short bf16_rtne(float f) {
    u32 u = __builtin_bit_cast(u32, f);
    u += 0x7fffu + ((u >> 16) & 1u);
    return (unsigned short)(u >> 16);
}

__device__ __forceinline__ u32 pk_bf16(float lo, float hi) {
    // D[15:0]=bf16(S0), D[31:16]=bf16(S1), RTNE
    u32 r;
    asm("v_cvt_pk_bf16_f32 %0, %1, %2" : "=v"(r) : "v"(lo), "v"(hi));
    return r;
}

__device__ __forceinline__ float fsigm(float x) {
    return __builtin_amdgcn_rcpf(1.0f + __expf(-x));
}
__device__ __forceinline__ float ftanh(float x) {
    return 1.0f - 2.0f * __builtin_amdgcn_rcpf(1.0f + __expf(2.0f * x));
}

// ---------------------------------------------------------------------------
// Precompute. Blocks 0..196: G table (inner index = gate g for coalesced
// writes; Wih row ~wave-uniform). Blocks 197..199: Whh -> bf16 hi/lo
// B-fragments in MFMA lane layout: B[k][unit], lane l holds k=8*(l>>4)+i,
// unit=16c+(l&15)  => Whh[unit][8*(l>>4)+i].
// ---------------------------------------------------------------------------
__global__ __launch_bounds__(256) void precomp(
    const float* __restrict__ emb,
    const float* __restrict__ Wih_f, const float* __restrict__ Whh_f,
    const float* __restrict__ bih_f, const float* __restrict__ bhh_f,
    const float* __restrict__ Wih_b, const float* __restrict__ Whh_b,
    const float* __restrict__ bih_b, const float* __restrict__ bhh_b,
    float* __restrict__ ws)
{
    int b = blockIdx.x;
    if (b < 197) {
        int idx = b * 256 + threadIdx.x;
        if (idx >= GFLOATS) return;
        int dir = idx / (Vv * G3);
        int rem = idx - dir * (Vv * G3);
        int v = rem / G3;
        int g = rem - v * G3;
        const float* Wih = dir ? Wih_b : Wih_f;
        float acc = (dir ? bih_b : bih_f)[g];
        if (g < 64) acc += (dir ? bhh_b : bhh_f)[g];   // fold bhh for r,z only
        const f32x4* er = (const f32x4*)(emb + v * Ee);
        const f32x4* wr = (const f32x4*)(Wih + g * Ee);
        float s = 0.0f;
        #pragma unroll
        for (int e = 0; e < 16; ++e) {
            f32x4 a = er[e], w = wr[e];
            s = fmaf(a[0], w[0], s);
            s = fmaf(a[1], w[1], s);
            s = fmaf(a[2], w[2], s);
            s = fmaf(a[3], w[3], s);
        }
        ws[idx] = acc + s;
    } else {
        int t = (b - 197) * 256 + threadIdx.x;
        if (t >= 768) return;
        int dir = t / 384;
        int r2  = t - dir * 384;
        int c   = r2 >> 6;          // unit chunk 0..5
        int l   = r2 & 63;          // lane
        int m   = l & 15, q = l >> 4;
        const float* Whh = dir ? Whh_b : Whh_f;
        const float* row = Whh + (16 * c + m) * Hh + 8 * q;
        u32 hiw[4], low[4];
        #pragma unroll
        for (int p = 0; p < 4; ++p) {
            float f0 = row[2 * p], f1 = row[2 * p + 1];
            unsigned short h0 = bf16_rtne(f0), h1 = bf16_rtne(f1);
            float rr0 = f0 - __builtin_bit_cast(float, (u32)h0 << 16);
            float rr1 = f1 - __builtin_bit_cast(float, (u32)h1 << 16);
            unsigned short l0 = bf16_rtne(rr0), l1 = bf16_rtne(rr1);
            hiw[p] = (u32)h0 | ((u32)h1 << 16);
            low[p] = (u32)l0 | ((u32)l1 << 16);
        }
        u32x4* dh = (u32x4*)(ws + BHI_FOFF) + (dir * 6 + c) * 64 + l;
        u32x4* dl = (u32x4*)(ws + BLO_FOFF) + (dir * 6 + c) * 64 + l;
        u32x4 vh = {hiw[0], hiw[1], hiw[2], hiw[3]};
        u32x4 vl = {low[0], low[1], low[2], low[3]};
        *dh = vh;
        *dl = vl;
    }
}

// ---------------------------------------------------------------------------
// Main: one wave = (16 words, 1 direction). MFMA 16x16x32 bf16, hi/lo split
// of h and Whh (3 accumulating MFMAs per 16-unit chunk -> ~fp32 precision).
// h state lives in D-layout frags: h[word=4q+r][unit=16c01+m]. Per-step
// transpose to A-layout via per-wave LDS slice (stride 33). No barriers.
// ---------------------------------------------------------------------------
__global__ __launch_bounds__(256, 2) void gru_main(
    const int*   __restrict__ x,
    const float* __restrict__ ws,
    const float* __restrict__ bhh_f,
    const float* __restrict__ bhh_b,
    float*       __restrict__ out)
{
    __shared__ float hbuf[4][16 * 33];   // per-wave transpose buffer
    __shared__ int   chs[4][16 * 17];    // per-wave char staging (stride 17)

    const int tid  = threadIdx.x;
    const int lane = tid & 63;
    const int widx = tid >> 6;
    const int wave = blockIdx.x * 4 + widx;
    const int dir  = wave & 1;
    const int wg   = wave >> 1;          // word-group 0..1023
    const int m = lane & 15, q = lane >> 4;

    // stage this wave's 16 words x 16 chars (contiguous 256 ints)
    {
        i32x4 cv = *(const i32x4*)(x + wg * 256 + lane * 4);
        #pragma unroll
        for (int j = 0; j < 4; ++j) {
            int p = lane * 4 + j;
            chs[widx][(p >> 4) * 17 + (p & 15)] = cv[j];
        }
    }

    // Whh B-fragments (hi/lo), coalesced 16B loads
    bf16x8 bhi[6], blo[6];
    {
        const u32x4* ph = (const u32x4*)(ws + BHI_FOFF) + dir * 384 + lane;
        const u32x4* pl = (const u32x4*)(ws + BLO_FOFF) + dir * 384 + lane;
        #pragma unroll
        for (int c = 0; c < 6; ++c) {
            bhi[c] = __builtin_bit_cast(bf16x8, ph[c * 64]);
            blo[c] = __builtin_bit_cast(bf16x8, pl[c * 64]);
        }
    }
    const float* bhh = dir ? bhh_b : bhh_f;
    const float bn0 = bhh[64 + m];       // bhh_n for units 0..15 (this lane's col)
    const float bn1 = bhh[80 + m];       // units 16..31
    const float* Gt = ws + dir * (Vv * G3);

    f32x4 h0v = {0.f, 0.f, 0.f, 0.f};    // h[4q+r][m]
    f32x4 h1v = {0.f, 0.f, 0.f, 0.f};    // h[4q+r][16+m]
    f32x4 mx0 = {-3e38f, -3e38f, -3e38f, -3e38f};
    f32x4 mx1 = {-3e38f, -3e38f, -3e38f, -3e38f};

    float* hb = hbuf[widx];
    int*   ch = chs[widx];
    const int t0 = dir ? 15 : 0;
    const int sg = dir ? -1 : 1;

    int cw0 = ch[(4 * q + 0) * 17 + t0];
    int cw1 = ch[(4 * q + 1) * 17 + t0];
    int cw2 = ch[(4 * q + 2) * 17 + t0];
    int cw3 = ch[(4 * q + 3) * 17 + t0];

    #pragma unroll 1
    for (int t = 0; t < 16; ++t) {
        // --- gi loads for this step (consumed ~200cy later by MFMA/gates) ---
        float gr0[4], gr1[4], gz0[4], gz1[4], gn0[4], gn1[4];
        {
            int cwr[4] = {cw0, cw1, cw2, cw3};
            #pragma unroll
            for (int r = 0; r < 4; ++r) {
                const float* gp = Gt + cwr[r] * G3 + m;
                gr0[r] = gp[0];  gr1[r] = gp[16];
                gz0[r] = gp[32]; gz1[r] = gp[48];
                gn0[r] = gp[64]; gn1[r] = gp[80];
            }
        }
        // --- prefetch next step's chars ---
        int nw0 = cw0, nw1 = cw1, nw2 = cw2, nw3 = cw3;
        if (t < 15) {
            int tt = t0 + sg * (t + 1);
            nw0 = ch[(4 * q + 0) * 17 + tt];
            nw1 = ch[(4 * q + 1) * 17 + tt];
            nw2 = ch[(4 * q + 2) * 17 + tt];
            nw3 = ch[(4 * q + 3) * 17 + tt];
        }
        // --- transpose h: write D-layout, read A-layout (same wave, DS in-order) ---
        #pragma unroll
        for (int r = 0; r < 4; ++r) {
            hb[(4 * q + r) * 33 + m]      = h0v[r];
            hb[(4 * q + r) * 33 + 16 + m] = h1v[r];
        }
        float a0 = hb[m * 33 + 8 * q + 0];
        float a1 = hb[m * 33 + 8 * q + 1];
        float a2 = hb[m * 33 + 8 * q + 2];
        float a3 = hb[m * 33 + 8 * q + 3];
        float a4 = hb[m * 33 + 8 * q + 4];
        float a5 = hb[m * 33 + 8 * q + 5];
        float a6 = hb[m * 33 + 8 * q + 6];
        float a7 = hb[m * 33 + 8 * q + 7];
        // --- split h into bf16 hi/lo A-fragments ---
        u32 w0 = pk_bf16(a0, a1), w1 = pk_bf16(a2, a3);
        u32 w2 = pk_bf16(a4, a5), w3 = pk_bf16(a6, a7);
        float e0 = __builtin_bit_cast(float, w0 << 16);
        float o0 = __builtin_bit_cast(float, w0 & 0xffff0000u);
        float e1 = __builtin_bit_cast(float, w1 << 16);
        float o1 = __builtin_bit_cast(float, w1 & 0xffff0000u);
        float e2 = __builtin_bit_cast(float, w2 << 16);
        float o2 = __builtin_bit_cast(float, w2 & 0xffff0000u);
        float e3 = __builtin_bit_cast(float, w3 << 16);
        float o3 = __builtin_bit_cast(float, w3 & 0xffff0000u);
        u32 v0 = pk_bf16(a0 - e0, a1 - o0);
        u32 v1 = pk_bf16(a2 - e1, a3 - o1);
        u32 v2 = pk_bf16(a4 - e2, a5 - o2);
        u32 v3 = pk_bf16(a6 - e3, a7 - o3);
        u32x4 hiq = {w0, w1, w2, w3};
        u32x4 loq = {v0, v1, v2, v3};
        bf16x8 Ahi = __builtin_bit_cast(bf16x8, hiq);
        bf16x8 Alo = __builtin_bit_cast(bf16x8, loq);

        // --- MFMA: acc_c = gi_c (or bhh_n) + h @ Whh^T chunk ---
        f32x4 ar0 = {gr0[0], gr0[1], gr0[2], gr0[3]};
        f32x4 ar1 = {gr1[0], gr1[1], gr1[2], gr1[3]};
        f32x4 az0 = {gz0[0], gz0[1], gz0[2], gz0[3]};
        f32x4 az1 = {gz1[0], gz1[1], gz1[2], gz1[3]};
        f32x4 an0 = {bn0, bn0, bn0, bn0};
        f32x4 an1 = {bn1, bn1, bn1, bn1};
        ar0 = __builtin_amdgcn_mfma_f32_16x16x32_bf16(Alo, bhi[0], ar0, 0, 0, 0);
        ar0 = __builtin_amdgcn_mfma_f32_16x16x32_bf16(Ahi, blo[0], ar0, 0, 0, 0);
        ar0 = __builtin_amdgcn_mfma_f32_16x16x32_bf16(Ahi, bhi[0], ar0, 0, 0, 0);
        ar1 = __builtin_amdgcn_mfma_f32_16x16x32_bf16(Alo, bhi[1], ar1, 0, 0, 0);
        ar1 = __builtin_amdgcn_mfma_f32_16x16x32_bf16(Ahi, blo[1], ar1, 0, 0, 0);
        ar1 = __builtin_amdgcn_mfma_f32_16x16x32_bf16(Ahi, bhi[1], ar1, 0, 0, 0);
        az0 = __builtin_amdgcn_mfma_f32_16x16x32_bf16(Alo, bhi[2], az0, 0, 0, 0);
        az0 = __builtin_amdgcn_mfma_f32_16x16x32_bf16(Ahi, blo[2], az0, 0, 0, 0);
        az0 = __builtin_amdgcn_mfma_f32_16x16x32_bf16(Ahi, bhi[2], az0, 0, 0, 0);
        az1 = __builtin_amdgcn_mfma_f32_16x16x32_bf16(Alo, bhi[3], az1, 0, 0, 0);
        az1 = __builtin_amdgcn_mfma_f32_16x16x32_bf16(Ahi, blo[3], az1, 0, 0, 0);
        az1 = __builtin_amdgcn_mfma_f32_16x16x32_bf16(Ahi, bhi[3], az1, 0, 0, 0);
        an0 = __builtin_amdgcn_mfma_f32_16x16x32_bf16(Alo, bhi[4], an0, 0, 0, 0);
        an0 = __builtin_amdgcn_mfma_f32_16x16x32_bf16(Ahi, blo[4], an0, 0, 0, 0);
        an0 = __builtin_amdgcn_mfma_f32_16x16x32_bf16(Ahi, bhi[4], an0, 0, 0, 0);
        an1 = __builtin_amdgcn_mfma_f32_16x16x32_bf16(Alo, bhi[5], an1, 0, 0, 0);
        an1 = __builtin_amdgcn_mfma_f32_16x16x32_bf16(Ahi, blo[5], an1, 0, 0, 0);
        an1 = __builtin_amdgcn_mfma_f32_16x16x32_bf16(Ahi, bhi[5], an1, 0, 0, 0);

        // --- gates + h update + running max ---
        #pragma unroll
        for (int r = 0; r < 4; ++r) {
            float rr0 = fsigm(ar0[r]);
            float zz0 = fsigm(az0[r]);
            float nn0 = ftanh(fmaf(rr0, an0[r], gn0[r]));
            float hx0 = nn0 + zz0 * (h0v[r] - nn0);
            mx0[r] = fmaxf(mx0[r], hx0);
            h0v[r] = hx0;

            float rr1 = fsigm(ar1[r]);
            float zz1 = fsigm(az1[r]);
            float nn1 = ftanh(fmaf(rr1, an1[r], gn1[r]));
            float hx1 = nn1 + zz1 * (h1v[r] - nn1);
            mx1[r] = fmaxf(mx1[r], hx1);
            h1v[r] = hx1;
        }
        cw0 = nw0; cw1 = nw1; cw2 = nw2; cw3 = nw3;
    }

    // --- store: out[word][dir*32 + unit], coalesced 64B per 16-lane group ---
    const int ob = wg * 16 * 64 + dir * 32;
    #pragma unroll
    for (int r = 0; r < 4; ++r) {
        out[ob + (4 * q + r) * 64 + m]      = mx0[r];
        out[ob + (4 * q + r) * 64 + 16 + m] = mx1[r];
    }
}

extern "C" void kernel_launch(void* const* d_in, const int* in_sizes, int n_in,
                              void* d_out, int out_size, void* d_ws, size_t ws_size,
                              hipStream_t stream) {
    const int*   x     = (const int*)  d_in[0];
    const float* emb   = (const float*)d_in[1];
    const float* Wih_f = (const float*)d_in[2];
    const float* Whh_f = (const float*)d_in[3];
    const float* bih_f = (const float*)d_in[4];
    const float* bhh_f = (const float*)d_in[5];
    const float* Wih_b = (const float*)d_in[6];
    const float* Whh_b = (const float*)d_in[7];
    const float* bih_b = (const float*)d_in[8];
    const float* bhh_b = (const float*)d_in[9];
    float* out = (float*)d_out;
    float* ws  = (float*)d_ws;

    precomp<<<200, 256, 0, stream>>>(emb, Wih_f, Whh_f, bih_f, bhh_f,
                                     Wih_b, Whh_b, bih_b, bhh_b, ws);
    gru_main<<<512, 256, 0, stream>>>(x, ws, bhh_f, bhh_b, out);
}